// Round 2
// baseline (429.554 us; speedup 1.0000x reference)
//
#include <hip/hip_runtime.h>

// ---------------------------------------------------------------------------
// VelocityEncoder fully-fused pipeline for MI355X (gfx950)
//   w2split: W2 (fp32 256x256) -> bf16 hi/lo planes, layout [kt=k>>5][n][k&31]
//   fused:   per block (64 rows):
//     phase1: per-row exact top-4-smallest (u64 keys = valbits<<32|idx, ties
//             by index == jax top_k), neighbor gather, combined@W1+b1, ReLU,
//             LayerNorm -> bf16 hi/lo written to swizzled LDS A-tile
//     phase2: out = h @ W2 + b2 via bf16x3 MFMA (32x32x16), A from LDS,
//             B direct from global (L2-resident), barrier-free
// ---------------------------------------------------------------------------

typedef __bf16 bf16x8 __attribute__((ext_vector_type(8)));
typedef unsigned short u16x8 __attribute__((ext_vector_type(8)));
typedef float f32x16 __attribute__((ext_vector_type(16)));

static __device__ __forceinline__ unsigned short f2bf(float x) {
    unsigned u = __float_as_uint(x);
    u += 0x7FFFu + ((u >> 16) & 1u);   // round-to-nearest-even
    return (unsigned short)(u >> 16);
}
static __device__ __forceinline__ float bf2f(unsigned short u) {
    return __uint_as_float(((unsigned)u) << 16);
}

#define UMIN64(a, b) ((a) < (b) ? (a) : (b))
#define CE64(x, y)                                                         \
    do {                                                                   \
        unsigned long long _mn = (x) < (y) ? (x) : (y);                    \
        unsigned long long _mx = (x) < (y) ? (y) : (x);                    \
        (x) = _mn; (y) = _mx;                                              \
    } while (0)

// ---------------------------------------------------------------------------
// W2 split: fp32 [k][n] -> bf16 hi/lo, layout [kt=k>>5][n][k&31]
// ---------------------------------------------------------------------------
__global__ __launch_bounds__(256) void w2split_kernel(
    const float* __restrict__ W2,
    unsigned short* __restrict__ bt_hi, unsigned short* __restrict__ bt_lo)
{
    const int k = blockIdx.x;    // 0..255
    const int n = threadIdx.x;   // 0..255
    const float w = W2[k * 256 + n];
    const unsigned short hi = f2bf(w);
    const unsigned short lo = f2bf(w - bf2f(hi));
    const size_t off = (size_t)(k >> 5) * 8192 + (size_t)n * 32 + (k & 31);
    bt_hi[off] = hi;
    bt_lo[off] = lo;
}

// ---------------------------------------------------------------------------
// LDS A-tile layout (ushort units), total 32768 ushorts = 64 KiB:
//   addr = kt*4096 + plane*2048 + (row>>1)*64 + phys*8 + elem
//   phys = (((row&1)<<2) | q) ^ ((row>>1)&7),  q = (k&31)>>3, elem = k&7
// ---------------------------------------------------------------------------

static __device__ __forceinline__ void process_row(
    float4 c0, float4 c1, float4 c2, float4 c3,
    int r, int lr, int lane,
    const float* __restrict__ vel,
    const float4 w1r0, const float4 w1r1, const float4 w1r2,
    const float4 w1r3, const float4 w1r4, const float4 w1r5,
    const float4 bb, const float4 g, const float4 be,
    unsigned short* __restrict__ A_lds)
{
    float v[16] = {c0.x, c0.y, c0.z, c0.w, c1.x, c1.y, c1.z, c1.w,
                   c2.x, c2.y, c2.z, c2.w, c3.x, c3.y, c3.z, c3.w};

    // per-lane sorted (ascending) top-4 of 16, 64-bit keys (bits<<32 | idx)
    unsigned long long k0 = ~0ull, k1 = ~0ull, k2 = ~0ull, k3 = ~0ull;
    #pragma unroll
    for (int j = 0; j < 4; ++j) {
        #pragma unroll
        for (int c = 0; c < 4; ++c) {
            const unsigned idx = (unsigned)(j * 256 + lane * 4 + c);
            const unsigned long long k =
                ((unsigned long long)__float_as_uint(v[j * 4 + c]) << 32) | idx;
            if (k < k3) {
                unsigned long long t1 = k0 < k ? k : k0;  k0 = UMIN64(k0, k);
                unsigned long long t2 = k1 < t1 ? t1 : k1; k1 = UMIN64(k1, t1);
                unsigned long long t3 = k2 < t2 ? t2 : k2; k2 = UMIN64(k2, t2);
                k3 = UMIN64(k3, t3);
            }
        }
    }

    // 6-level bitonic top-4 allreduce across 64 lanes
    #pragma unroll
    for (int s = 1; s < 64; s <<= 1) {
        unsigned long long p0 = __shfl_xor(k0, s);
        unsigned long long p1 = __shfl_xor(k1, s);
        unsigned long long p2 = __shfl_xor(k2, s);
        unsigned long long p3 = __shfl_xor(k3, s);
        unsigned long long l0 = UMIN64(k0, p3);
        unsigned long long l1 = UMIN64(k1, p2);
        unsigned long long l2 = UMIN64(k2, p1);
        unsigned long long l3 = UMIN64(k3, p0);
        CE64(l0, l2); CE64(l1, l3); CE64(l0, l1); CE64(l2, l3);
        k0 = l0; k1 = l1; k2 = l2; k3 = l3;
    }
    // neighbors = 2nd..4th smallest (reference drops idx[...,0])
    const unsigned i1 = (unsigned)k1, i2 = (unsigned)k2, i3 = (unsigned)k3;

    const float* va = vel + (size_t)r * 3;
    const size_t vb = (size_t)((r >> 10) << 10) * 3;
    const float* n1 = vel + vb + (size_t)i1 * 3;
    const float* n2 = vel + vb + (size_t)i2 * 3;
    const float* n3 = vel + vb + (size_t)i3 * 3;
    const float ax = va[0], ay = va[1], az = va[2];
    const float mx = (n1[0] + n2[0] + n3[0]) * (1.0f / 3.0f);
    const float my = (n1[1] + n2[1] + n3[1]) * (1.0f / 3.0f);
    const float mz = (n1[2] + n2[2] + n3[2]) * (1.0f / 3.0f);
    const float cb[6] = {ax, ay, az, ax - mx, ay - my, az - mz};

    // h[e] for e = lane*4 .. lane*4+3
    float h0 = bb.x, h1 = bb.y, h2 = bb.z, h3 = bb.w;
    h0 = fmaf(cb[0], w1r0.x, h0); h1 = fmaf(cb[0], w1r0.y, h1);
    h2 = fmaf(cb[0], w1r0.z, h2); h3 = fmaf(cb[0], w1r0.w, h3);
    h0 = fmaf(cb[1], w1r1.x, h0); h1 = fmaf(cb[1], w1r1.y, h1);
    h2 = fmaf(cb[1], w1r1.z, h2); h3 = fmaf(cb[1], w1r1.w, h3);
    h0 = fmaf(cb[2], w1r2.x, h0); h1 = fmaf(cb[2], w1r2.y, h1);
    h2 = fmaf(cb[2], w1r2.z, h2); h3 = fmaf(cb[2], w1r2.w, h3);
    h0 = fmaf(cb[3], w1r3.x, h0); h1 = fmaf(cb[3], w1r3.y, h1);
    h2 = fmaf(cb[3], w1r3.z, h2); h3 = fmaf(cb[3], w1r3.w, h3);
    h0 = fmaf(cb[4], w1r4.x, h0); h1 = fmaf(cb[4], w1r4.y, h1);
    h2 = fmaf(cb[4], w1r4.z, h2); h3 = fmaf(cb[4], w1r4.w, h3);
    h0 = fmaf(cb[5], w1r5.x, h0); h1 = fmaf(cb[5], w1r5.y, h1);
    h2 = fmaf(cb[5], w1r5.z, h2); h3 = fmaf(cb[5], w1r5.w, h3);
    h0 = fmaxf(h0, 0.f); h1 = fmaxf(h1, 0.f);
    h2 = fmaxf(h2, 0.f); h3 = fmaxf(h3, 0.f);

    // LayerNorm over 256 channels (wave reduce)
    float s = h0 + h1 + h2 + h3;
    float s2 = h0 * h0 + h1 * h1 + h2 * h2 + h3 * h3;
    #pragma unroll
    for (int o = 32; o; o >>= 1) {
        s += __shfl_xor(s, o);
        s2 += __shfl_xor(s2, o);
    }
    const float mu = s * (1.0f / 256.0f);
    const float var = s2 * (1.0f / 256.0f) - mu * mu;
    const float inv = rsqrtf(var + 1e-5f);
    const float y0 = (h0 - mu) * inv * g.x + be.x;
    const float y1 = (h1 - mu) * inv * g.y + be.y;
    const float y2 = (h2 - mu) * inv * g.z + be.z;
    const float y3 = (h3 - mu) * inv * g.w + be.w;

    ushort4 hv, lv;
    hv.x = f2bf(y0); lv.x = f2bf(y0 - bf2f(hv.x));
    hv.y = f2bf(y1); lv.y = f2bf(y1 - bf2f(hv.y));
    hv.z = f2bf(y2); lv.z = f2bf(y2 - bf2f(hv.z));
    hv.w = f2bf(y3); lv.w = f2bf(y3 - bf2f(hv.w));

    // swizzled LDS write: e0 = lane*4 -> kt = lane>>3, q = (lane>>1)&3,
    // elem = (lane&1)*4
    const int pr = lr >> 1;
    const int phys = ((((lr & 1) << 2) | ((lane >> 1) & 3)) ^ (pr & 7));
    const int base = (lane >> 3) * 4096 + pr * 64 + phys * 8 + (lane & 1) * 4;
    *(ushort4*)(A_lds + base) = hv;
    *(ushort4*)(A_lds + base + 2048) = lv;
}

#define MFMA(acc, a, b) \
    (acc) = __builtin_amdgcn_mfma_f32_32x32x16_bf16((a), (b), (acc), 0, 0, 0)

__global__ __launch_bounds__(512, 4) void fused_kernel(
    const float* __restrict__ vel, const float* __restrict__ dist,
    const float* __restrict__ W1, const float* __restrict__ b1,
    const float* __restrict__ gammav, const float* __restrict__ betav,
    const unsigned short* __restrict__ bt_hi, const unsigned short* __restrict__ bt_lo,
    const float* __restrict__ b2, float* __restrict__ out)
{
    __shared__ __align__(16) unsigned short A_lds[32768];   // 64 KiB

    const int tid = threadIdx.x;
    const int lane = tid & 63;
    const int wid = tid >> 6;        // 0..7
    const int l31 = lane & 31;
    const int lh = lane >> 5;
    const int rowB = blockIdx.x * 64;

    // ---------------- phase 1: 8 rows per wave ----------------
    {
        const int e0 = lane * 4;
        const float4 w1r0 = *(const float4*)(W1 + 0 * 256 + e0);
        const float4 w1r1 = *(const float4*)(W1 + 1 * 256 + e0);
        const float4 w1r2 = *(const float4*)(W1 + 2 * 256 + e0);
        const float4 w1r3 = *(const float4*)(W1 + 3 * 256 + e0);
        const float4 w1r4 = *(const float4*)(W1 + 4 * 256 + e0);
        const float4 w1r5 = *(const float4*)(W1 + 5 * 256 + e0);
        const float4 bb = *(const float4*)(b1 + e0);
        const float4 g  = *(const float4*)(gammav + e0);
        const float4 be = *(const float4*)(betav + e0);

        int r = rowB + wid * 8;
        const float* dp = dist + (size_t)r * 1024 + lane * 4;
        float4 c0 = *(const float4*)(dp);
        float4 c1 = *(const float4*)(dp + 256);
        float4 c2 = *(const float4*)(dp + 512);
        float4 c3 = *(const float4*)(dp + 768);
        #pragma unroll
        for (int i = 0; i < 8; ++i) {
            float4 n0, n1, n2, n3;
            if (i < 7) {   // prefetch next row while current row computes
                const float* dn = dist + (size_t)(r + 1) * 1024 + lane * 4;
                n0 = *(const float4*)(dn);
                n1 = *(const float4*)(dn + 256);
                n2 = *(const float4*)(dn + 512);
                n3 = *(const float4*)(dn + 768);
            }
            process_row(c0, c1, c2, c3, r, wid * 8 + i, lane, vel,
                        w1r0, w1r1, w1r2, w1r3, w1r4, w1r5, bb, g, be, A_lds);
            c0 = n0; c1 = n1; c2 = n2; c3 = n3;
            ++r;
        }
    }
    __syncthreads();

    // ---------------- phase 2: barrier-free GEMM ----------------
    const int wm = wid >> 2;         // 0..1  (M 32-row half)
    const int wn = wid & 3;          // 0..3  (N 64-col group)

    f32x16 acc0, acc1;
    #pragma unroll
    for (int i = 0; i < 16; ++i) { acc0[i] = 0.f; acc1[i] = 0.f; }

    // A fragment address pieces: row = wm*32 + l31
    const int arow = wm * 32 + l31;
    const int aB = (arow >> 1) * 64;
    const int aK = ((arow & 1) << 2) ^ ((arow >> 1) & 7);
    // B fragment: cols n0 = wn*64 + l31, n1 = n0 + 32
    const int n0 = wn * 64 + l31;
    const unsigned short* bh0 = bt_hi + n0 * 32;
    const unsigned short* bl0 = bt_lo + n0 * 32;
    const unsigned short* bh1 = bh0 + 32 * 32;
    const unsigned short* bl1 = bl0 + 32 * 32;

    #define LDS_F(off) __builtin_bit_cast(bf16x8, *(const u16x8*)(A_lds + (off)))
    #define GLB_F(p)   __builtin_bit_cast(bf16x8, *(const u16x8*)(p))

    #pragma unroll
    for (int kt = 0; kt < 8; ++kt) {
        #pragma unroll
        for (int ks = 0; ks < 2; ++ks) {
            const int q = ks * 2 + lh;
            const int aoff = kt * 4096 + aB + ((aK ^ q) << 3);
            const int boff = kt * 8192 + q * 8;
            bf16x8 ah = LDS_F(aoff);
            bf16x8 al = LDS_F(aoff + 2048);
            bf16x8 b0h = GLB_F(bh0 + boff);
            bf16x8 b0l = GLB_F(bl0 + boff);
            bf16x8 b1h = GLB_F(bh1 + boff);
            bf16x8 b1l = GLB_F(bl1 + boff);
            MFMA(acc0, ah, b0h); MFMA(acc0, ah, b0l); MFMA(acc0, al, b0h);
            MFMA(acc1, ah, b1h); MFMA(acc1, ah, b1l); MFMA(acc1, al, b1h);
        }
    }

    // epilogue: C/D layout col = lane&31, row = (reg&3) + 8*(reg>>2) + 4*lh
    const int col0 = wn * 64 + l31;
    const int col1 = col0 + 32;
    const float bias0 = b2[col0];
    const float bias1 = b2[col1];
    #pragma unroll
    for (int q2 = 0; q2 < 4; ++q2) {
        #pragma unroll
        for (int j = 0; j < 4; ++j) {
            const int reg = q2 * 4 + j;
            const size_t rg = (size_t)(rowB + wm * 32 + j + 8 * q2 + 4 * lh);
            out[rg * 256 + col0] = acc0[reg] + bias0;
            out[rg * 256 + col1] = acc1[reg] + bias1;
        }
    }
}

// ---------------------------------------------------------------------------
extern "C" void kernel_launch(void* const* d_in, const int* in_sizes, int n_in,
                              void* d_out, int out_size, void* d_ws, size_t ws_size,
                              hipStream_t stream)
{
    const float* vel   = (const float*)d_in[0];
    const float* dist  = (const float*)d_in[1];
    const float* W1    = (const float*)d_in[2];
    const float* b1    = (const float*)d_in[3];
    const float* gam   = (const float*)d_in[4];
    const float* bet   = (const float*)d_in[5];
    const float* W2    = (const float*)d_in[6];
    const float* b2    = (const float*)d_in[7];
    float* out = (float*)d_out;

    unsigned short* bt_hi = (unsigned short*)d_ws;       // 256x256
    unsigned short* bt_lo = bt_hi + 65536ull;

    w2split_kernel<<<256, 256, 0, stream>>>(W2, bt_hi, bt_lo);
    fused_kernel<<<1024, 512, 0, stream>>>(vel, dist, W1, b1, gam, bet,
                                           bt_hi, bt_lo, b2, out);
}